// Round 11
// baseline (218.629 us; speedup 1.0000x reference)
//
#include <hip/hip_runtime.h>

// ---------------- problem constants ----------------
// B*P=32, N=512, D=128, H=4, DK=32, T=3 (tm {0,1,3}; tsel(t)=t+(t>>1))
// Inputs f32, OUTPUT f32. XL path confirmed running (R10).
// R10 post-mortem: k_attn 74us limited by 16 scattered scalar f32 tm loads
// + f2b VALU chains per chunk; qkv/oproj parallelism-starved (1-1.5 blk/CU).
// R11: tmT bf16 transposed (one 8B load per ti), bit-add half-up P rounding,
// qkv split to 1152 blocks (Xb dropped), oproj split to 512 blocks with
// cross-wave LDS LayerNorm reduction.

typedef __attribute__((ext_vector_type(8))) short  short8;
typedef __attribute__((ext_vector_type(4))) float  floatx4;
typedef __attribute__((ext_vector_type(4))) unsigned short u16x4;

#define WS_BIG   50331648ull                  // q3/k3/v3 (37.7MB) + att (12.6MB)
#define WS_XL    52297728ull                  // + Wb 288KB + Wob 96KB + tmT 1.5MB
#define QSCALE   0.25503486f                  // (1/sqrt(32)) * log2(e)

__device__ __forceinline__ float b2f(unsigned short u) {
    union { unsigned int i; float f; } v; v.i = ((unsigned int)u) << 16; return v.f;
}
__device__ __forceinline__ unsigned short f2b(float f) {
    union { float f; unsigned int i; } v; v.f = f;
    unsigned int x = v.i;
    return (unsigned short)((x + 0x7fffu + ((x >> 16) & 1u)) >> 16);
}
__device__ __forceinline__ unsigned int fbits(float f) {
    union { float f; unsigned int i; } v; v.f = f; return v.i;
}
__device__ __forceinline__ short8 cvt8(const float* p) {
    floatx4 a = *(const floatx4*)p;
    floatx4 b = *(const floatx4*)(p + 4);
    short8 r;
    r[0] = (short)f2b(a[0]); r[1] = (short)f2b(a[1]);
    r[2] = (short)f2b(a[2]); r[3] = (short)f2b(a[3]);
    r[4] = (short)f2b(b[0]); r[5] = (short)f2b(b[1]);
    r[6] = (short)f2b(b[2]); r[7] = (short)f2b(b[3]);
    return r;
}

// ---------------- K0: prep — W/Wo -> bf16, tm -> bf16 TRANSPOSED ----------------
// grid 288: blocks 0..95 convert Wq/Wk/Wv/Wo (2048 elems each);
// blocks 96..287 transpose one 64x64 tile of one tm matrix (LDS transpose).
__global__ __launch_bounds__(256) void k_prep(
    const float* __restrict__ Wq, const float* __restrict__ Wk,
    const float* __restrict__ Wv, const float* __restrict__ Wo,
    const float* __restrict__ TM,            // [4][512][512] f32
    unsigned short* __restrict__ Wb,         // [3 qkv][3 t][128][128] bf16
    unsigned short* __restrict__ Wob,        // [128][384] bf16
    unsigned short* __restrict__ tmT)        // [3][512 m][512 n] bf16 (transposed)
{
    int bid = blockIdx.x, tid = threadIdx.x;
    if (bid < 96) {
        size_t i = (size_t)bid * 2048 + tid * 8;
        const float* src; unsigned short* dst; size_t off;
        if      (i <  49152) { src = Wq; dst = Wb;          off = i; }
        else if (i <  98304) { src = Wk; dst = Wb + 49152;  off = i - 49152; }
        else if (i < 147456) { src = Wv; dst = Wb + 98304;  off = i - 98304; }
        else                 { src = Wo; dst = Wob;         off = i - 147456; }
        *(short8*)&dst[off] = cvt8(&src[off]);
        return;
    }
    // tm transpose: 64x64 tile
    __shared__ float Tl[64][65];
    int r = bid - 96;
    int t = r >> 6, tile = r & 63;
    int ntile = tile >> 3, mtile = tile & 7;
    const float* tmsrc = TM + (size_t)(t + (t >> 1)) * 262144;
    {
        int row = tid >> 2, cseg = (tid & 3) * 16;
        const float* p = &tmsrc[(size_t)(ntile * 64 + row) * 512 + mtile * 64 + cseg];
        #pragma unroll
        for (int j = 0; j < 4; ++j)
            *(floatx4*)&Tl[row][cseg + j * 4] = *(const floatx4*)&p[j * 4];
    }
    __syncthreads();
    {
        int m = tid >> 2, nseg = (tid & 3) * 16;
        unsigned short* q = &tmT[(size_t)t * 262144 +
                                 (size_t)(mtile * 64 + m) * 512 + ntile * 64 + nseg];
        short8 o0, o1;
        #pragma unroll
        for (int j = 0; j < 8; ++j) {
            o0[j] = (short)f2b(Tl[nseg + j][m]);
            o1[j] = (short)f2b(Tl[nseg + 8 + j][m]);
        }
        *(short8*)&q[0] = o0;
        *(short8*)&q[8] = o1;
    }
}

// ---------------- K1a: QKV projection, split grid (bp=32, mt=4, z=9) ----------
// z = t*3 + qkv. X converted inline (cheap, once per block); W from Wb bf16.
__global__ __launch_bounds__(256) void k_qkv2(
    const float* __restrict__ X,             // [32][512][128] f32
    const unsigned short* __restrict__ Wb,   // [3 qkv][3 t][128][128] bf16
    unsigned short* __restrict__ q_ws,
    unsigned short* __restrict__ k_ws,
    unsigned short* __restrict__ v_ws)
{
    int bp = blockIdx.x, mt = blockIdx.y, z = blockIdx.z;
    int t = z / 3, qkv = z - t * 3;
    __shared__ unsigned short Xs[128 * 128];     // 32 KB
    int tid = threadIdx.x;
    int lane = tid & 63, wv = tid >> 6;
    int l15 = lane & 15, quad = lane >> 4;

    const float* Xbase = X + ((size_t)bp * 512 + mt * 128) * 128;
    for (int i = 0; i < 8; ++i) {
        int e = (i * 256 + tid) * 8;
        *(short8*)&Xs[e] = cvt8(&Xbase[e]);
    }
    __syncthreads();

    const unsigned short* Wt = Wb + qkv * 49152 + t * 16384;
    unsigned short* Ob = (qkv == 0 ? q_ws : qkv == 1 ? k_ws : v_ws)
                       + (size_t)t * 2097152 + ((size_t)bp * 512 + mt * 128) * 128;
    float sc = (qkv == 0) ? QSCALE : 1.0f;

    for (int ct = 0; ct < 8; ++ct) {
        short8 bfr[4];
        for (int kk = 0; kk < 4; ++kk)
            bfr[kk] = *(const short8*)&Wt[(size_t)(ct * 16 + l15) * 128 + kk * 32 + quad * 8];
        floatx4 acc0 = {0.f, 0.f, 0.f, 0.f};
        floatx4 acc1 = {0.f, 0.f, 0.f, 0.f};
        int rt0 = wv * 2, rt1 = wv * 2 + 1;
        for (int kk = 0; kk < 4; ++kk) {
            short8 a0 = *(const short8*)&Xs[(rt0 * 16 + l15) * 128 + kk * 32 + quad * 8];
            short8 a1 = *(const short8*)&Xs[(rt1 * 16 + l15) * 128 + kk * 32 + quad * 8];
            acc0 = __builtin_amdgcn_mfma_f32_16x16x32_bf16(a0, bfr[kk], acc0, 0, 0, 0);
            acc1 = __builtin_amdgcn_mfma_f32_16x16x32_bf16(a1, bfr[kk], acc1, 0, 0, 0);
        }
        int col = ct * 16 + l15;
        for (int i = 0; i < 4; ++i) {
            Ob[(size_t)(rt0 * 16 + quad * 4 + i) * 128 + col] = f2b(acc0[i] * sc);
            Ob[(size_t)(rt1 * 16 + quad * 4 + i) * 128 + col] = f2b(acc1[i] * sc);
        }
    }
}

// ---------------- K1b: QKV projection, inline-cvt fallback (R8-proven) --------
__global__ __launch_bounds__(256) void k_qkv_cvt(
    const float* __restrict__ X,
    const float* __restrict__ Wq, const float* __restrict__ Wk,
    const float* __restrict__ Wv,
    unsigned short* __restrict__ q_ws, unsigned short* __restrict__ k_ws,
    unsigned short* __restrict__ v_ws,
    int wstride, int ostride)
{
    int bp = blockIdx.x, mt = blockIdx.y, tz = blockIdx.z;
    __shared__ unsigned short Xs[128 * 128];
    int tid = threadIdx.x;
    int lane = tid & 63, wv = tid >> 6;
    int l15 = lane & 15, quad = lane >> 4;

    const float* Xbase = X + ((size_t)bp * 512 + mt * 128) * 128;
    for (int i = 0; i < 8; ++i) {
        int e = (i * 256 + tid) * 8;
        *(short8*)&Xs[e] = cvt8(&Xbase[e]);
    }
    __syncthreads();

    size_t woff = (size_t)tz * wstride;
    size_t ooff = (size_t)tz * ostride;
    const float* Wsel[3] = { Wq + woff, Wk + woff, Wv + woff };
    unsigned short* Osel[3] = { q_ws + ooff, k_ws + ooff, v_ws + ooff };

    for (int qkv = 0; qkv < 3; ++qkv) {
        const float* Wt = Wsel[qkv];
        unsigned short* Ob = Osel[qkv] + ((size_t)bp * 512 + mt * 128) * 128;
        float sc = (qkv == 0) ? QSCALE : 1.0f;
        for (int ct = 0; ct < 8; ++ct) {
            short8 bfr[4];
            for (int kk = 0; kk < 4; ++kk)
                bfr[kk] = cvt8(&Wt[(size_t)(ct * 16 + l15) * 128 + kk * 32 + quad * 8]);
            floatx4 acc0 = {0.f, 0.f, 0.f, 0.f};
            floatx4 acc1 = {0.f, 0.f, 0.f, 0.f};
            int rt0 = wv * 2, rt1 = wv * 2 + 1;
            for (int kk = 0; kk < 4; ++kk) {
                short8 a0 = *(const short8*)&Xs[(rt0 * 16 + l15) * 128 + kk * 32 + quad * 8];
                short8 a1 = *(const short8*)&Xs[(rt1 * 16 + l15) * 128 + kk * 32 + quad * 8];
                acc0 = __builtin_amdgcn_mfma_f32_16x16x32_bf16(a0, bfr[kk], acc0, 0, 0, 0);
                acc1 = __builtin_amdgcn_mfma_f32_16x16x32_bf16(a1, bfr[kk], acc1, 0, 0, 0);
            }
            int col = ct * 16 + l15;
            for (int i = 0; i < 4; ++i) {
                Ob[(size_t)(rt0 * 16 + quad * 4 + i) * 128 + col] = f2b(acc0[i] * sc);
                Ob[(size_t)(rt1 * 16 + quad * 4 + i) * 128 + col] = f2b(acc1[i] * sc);
            }
        }
    }
}

// ---------------- K2a: dense MFMA attention with transposed bf16 tm ----------
// Per ti: ONE 8-byte tmT load gives the 4 row values; P stored via bit-add
// half-up rounding (2 VALU). Everything else = R10-proven structure.
__global__ __launch_bounds__(512) void k_attn_t(
    const unsigned short* __restrict__ q_ws,   // bf16, pre-scaled by QSCALE
    const unsigned short* __restrict__ k_ws,
    const unsigned short* __restrict__ v_ws,
    const unsigned short* __restrict__ tmT,    // [3][512 m][512 n] bf16
    unsigned short* __restrict__ att_ws)       // [32][512][384] bf16
{
    int nc = blockIdx.x;
    int bp = blockIdx.y;
    int z  = blockIdx.z;
    int t = z >> 2, h = z & 3;
    size_t qoff = (size_t)t * 2097152;
    const unsigned short* tmt = tmT + (size_t)t * 262144;

    __shared__ unsigned short Vt[32][516];
    __shared__ unsigned short Ps[8][16][72];

    int tid = threadIdx.x, lane = tid & 63, wv = tid >> 6;
    int l15 = lane & 15, quad = lane >> 4;

    {
        const unsigned short* vp = v_ws + qoff + ((size_t)bp * 512 + tid) * 128 + h * 32;
        short8 a = *(const short8*)vp;
        short8 b = *(const short8*)(vp + 8);
        short8 c = *(const short8*)(vp + 16);
        short8 d = *(const short8*)(vp + 24);
        #pragma unroll
        for (int j = 0; j < 8; ++j) {
            Vt[j][tid]      = (unsigned short)a[j];
            Vt[8 + j][tid]  = (unsigned short)b[j];
            Vt[16 + j][tid] = (unsigned short)c[j];
            Vt[24 + j][tid] = (unsigned short)d[j];
        }
    }
    int n0 = nc * 128 + wv * 16;
    short8 qf = *(const short8*)&q_ws[qoff +
        ((size_t)bp * 512 + n0 + l15) * 128 + h * 32 + quad * 8];
    __syncthreads();

    const unsigned short* Kb = k_ws + qoff + (size_t)bp * 512 * 128 + h * 32;
    floatx4 O0 = {0.f, 0.f, 0.f, 0.f};
    floatx4 O1 = {0.f, 0.f, 0.f, 0.f};
    float za[4] = {0.f, 0.f, 0.f, 0.f};
    const floatx4 zero4 = {0.f, 0.f, 0.f, 0.f};

    for (int c = 0; c < 8; ++c) {
        int mb = c * 64;
        short8 kf0 = *(const short8*)&Kb[(size_t)(mb +  0 + l15) * 128 + quad * 8];
        short8 kf1 = *(const short8*)&Kb[(size_t)(mb + 16 + l15) * 128 + quad * 8];
        short8 kf2 = *(const short8*)&Kb[(size_t)(mb + 32 + l15) * 128 + quad * 8];
        short8 kf3 = *(const short8*)&Kb[(size_t)(mb + 48 + l15) * 128 + quad * 8];
        // hoist all 4 tm vector loads (overlap latency with MFMA + exp chain)
        u16x4 t4[4];
        #pragma unroll
        for (int ti = 0; ti < 4; ++ti)
            t4[ti] = *(const u16x4*)&tmt[(size_t)(mb + ti * 16 + l15) * 512 + n0 + quad * 4];
        floatx4 S[4];
        S[0] = __builtin_amdgcn_mfma_f32_16x16x32_bf16(qf, kf0, zero4, 0, 0, 0);
        S[1] = __builtin_amdgcn_mfma_f32_16x16x32_bf16(qf, kf1, zero4, 0, 0, 0);
        S[2] = __builtin_amdgcn_mfma_f32_16x16x32_bf16(qf, kf2, zero4, 0, 0, 0);
        S[3] = __builtin_amdgcn_mfma_f32_16x16x32_bf16(qf, kf3, zero4, 0, 0, 0);

        #pragma unroll
        for (int ti = 0; ti < 4; ++ti) {
            #pragma unroll
            for (int i = 0; i < 4; ++i) {
                unsigned short tv = t4[ti][i];
                float e = __builtin_amdgcn_exp2f(S[ti][i]);
                bool on = (tv != 0);
                za[i] += on ? e : 0.0f;
                float w = on ? e * b2f(tv) : 0.0f;
                // half-up round to bf16: bit-add then take high 16
                Ps[wv][quad * 4 + i][ti * 16 + l15] =
                    (unsigned short)((fbits(w) + 0x8000u) >> 16);
            }
        }
        #pragma unroll
        for (int kc = 0; kc < 2; ++kc) {
            short8 pa  = *(const short8*)&Ps[wv][l15][kc * 32 + quad * 8];
            short8 vb0 = *(const short8*)&Vt[l15][mb + kc * 32 + quad * 8];
            short8 vb1 = *(const short8*)&Vt[16 + l15][mb + kc * 32 + quad * 8];
            O0 = __builtin_amdgcn_mfma_f32_16x16x32_bf16(pa, vb0, O0, 0, 0, 0);
            O1 = __builtin_amdgcn_mfma_f32_16x16x32_bf16(pa, vb1, O1, 0, 0, 0);
        }
    }

    #pragma unroll
    for (int d = 1; d < 16; d <<= 1) {
        #pragma unroll
        for (int i = 0; i < 4; ++i) za[i] += __shfl_xor(za[i], d, 64);
    }
    #pragma unroll
    for (int i = 0; i < 4; ++i) {
        float rz = 1.0f / za[i];
        size_t row = (size_t)bp * 512 + n0 + quad * 4 + i;
        att_ws[row * 384 + t * 128 + h * 32 + l15]      = f2b(O0[i] * rz);
        att_ws[row * 384 + t * 128 + h * 32 + 16 + l15] = f2b(O1[i] * rz);
    }
}

// ---------------- K2b: R10-proven attention (f32 tm) for fallback paths -------
__global__ __launch_bounds__(512) void k_attn_f32(
    const unsigned short* __restrict__ q_ws,
    const unsigned short* __restrict__ k_ws,
    const unsigned short* __restrict__ v_ws,
    const float* __restrict__ tm,
    unsigned short* __restrict__ att_ws,
    int qkv_stride, int toff0)
{
    int nc = blockIdx.x;
    int bp = blockIdx.y;
    int z  = blockIdx.z;
    int t = z >> 2, h = z & 3;
    size_t qoff = (size_t)t * (size_t)qkv_stride;
    const float* tmt = tm + (size_t)(t + (t >> 1)) * 262144;
    int toff = toff0 + t * 128;

    __shared__ unsigned short Vt[32][516];
    __shared__ unsigned short Ps[8][16][72];

    int tid = threadIdx.x, lane = tid & 63, wv = tid >> 6;
    int l15 = lane & 15, quad = lane >> 4;

    {
        const unsigned short* vp = v_ws + qoff + ((size_t)bp * 512 + tid) * 128 + h * 32;
        short8 a = *(const short8*)vp;
        short8 b = *(const short8*)(vp + 8);
        short8 c = *(const short8*)(vp + 16);
        short8 d = *(const short8*)(vp + 24);
        #pragma unroll
        for (int j = 0; j < 8; ++j) {
            Vt[j][tid]      = (unsigned short)a[j];
            Vt[8 + j][tid]  = (unsigned short)b[j];
            Vt[16 + j][tid] = (unsigned short)c[j];
            Vt[24 + j][tid] = (unsigned short)d[j];
        }
    }
    int n0 = nc * 128 + wv * 16;
    short8 qf = *(const short8*)&q_ws[qoff +
        ((size_t)bp * 512 + n0 + l15) * 128 + h * 32 + quad * 8];
    __syncthreads();

    const unsigned short* Kb = k_ws + qoff + (size_t)bp * 512 * 128 + h * 32;
    floatx4 O0 = {0.f, 0.f, 0.f, 0.f};
    floatx4 O1 = {0.f, 0.f, 0.f, 0.f};
    float za[4] = {0.f, 0.f, 0.f, 0.f};
    const floatx4 zero4 = {0.f, 0.f, 0.f, 0.f};

    for (int c = 0; c < 8; ++c) {
        int mb = c * 64;
        short8 kf0 = *(const short8*)&Kb[(size_t)(mb +  0 + l15) * 128 + quad * 8];
        short8 kf1 = *(const short8*)&Kb[(size_t)(mb + 16 + l15) * 128 + quad * 8];
        short8 kf2 = *(const short8*)&Kb[(size_t)(mb + 32 + l15) * 128 + quad * 8];
        short8 kf3 = *(const short8*)&Kb[(size_t)(mb + 48 + l15) * 128 + quad * 8];
        floatx4 S[4];
        S[0] = __builtin_amdgcn_mfma_f32_16x16x32_bf16(qf, kf0, zero4, 0, 0, 0);
        S[1] = __builtin_amdgcn_mfma_f32_16x16x32_bf16(qf, kf1, zero4, 0, 0, 0);
        S[2] = __builtin_amdgcn_mfma_f32_16x16x32_bf16(qf, kf2, zero4, 0, 0, 0);
        S[3] = __builtin_amdgcn_mfma_f32_16x16x32_bf16(qf, kf3, zero4, 0, 0, 0);

        #pragma unroll
        for (int ti = 0; ti < 4; ++ti) {
            int m = mb + ti * 16 + l15;
            #pragma unroll
            for (int i = 0; i < 4; ++i) {
                float tmv = tmt[(size_t)(n0 + quad * 4 + i) * 512 + m];
                float e = __builtin_amdgcn_exp2f(S[ti][i]);
                bool on = (tmv != 0.0f);
                za[i] += on ? e : 0.0f;
                float w = on ? e * tmv : 0.0f;
                Ps[wv][quad * 4 + i][ti * 16 + l15] = f2b(w);
            }
        }
        #pragma unroll
        for (int kc = 0; kc < 2; ++kc) {
            short8 pa  = *(const short8*)&Ps[wv][l15][kc * 32 + quad * 8];
            short8 vb0 = *(const short8*)&Vt[l15][mb + kc * 32 + quad * 8];
            short8 vb1 = *(const short8*)&Vt[16 + l15][mb + kc * 32 + quad * 8];
            O0 = __builtin_amdgcn_mfma_f32_16x16x32_bf16(pa, vb0, O0, 0, 0, 0);
            O1 = __builtin_amdgcn_mfma_f32_16x16x32_bf16(pa, vb1, O1, 0, 0, 0);
        }
    }

    #pragma unroll
    for (int d = 1; d < 16; d <<= 1) {
        #pragma unroll
        for (int i = 0; i < 4; ++i) za[i] += __shfl_xor(za[i], d, 64);
    }
    #pragma unroll
    for (int i = 0; i < 4; ++i) {
        float rz = 1.0f / za[i];
        size_t row = (size_t)bp * 512 + n0 + quad * 4 + i;
        att_ws[row * 384 + toff + h * 32 + l15]      = f2b(O0[i] * rz);
        att_ws[row * 384 + toff + h * 32 + 16 + l15] = f2b(O1[i] * rz);
    }
}

// ---------------- K3a: out-projection, 512 blocks (32 rows each) -------------
// grid (bp=32, mt=16). 4 waves: rt = wv>>1 (row tile), ch = wv&1 (ct half).
// LayerNorm needs full 128-col rows -> cross-wave-pair partial-sum via LDS.
__global__ __launch_bounds__(256) void k_oproj2(
    const unsigned short* __restrict__ att_ws,   // [32][512][384] bf16
    const unsigned short* __restrict__ Wob,      // [128][384] bf16
    const float* __restrict__ X,
    const float* __restrict__ gamma,
    const float* __restrict__ beta,
    float* __restrict__ out)
{
    int bp = blockIdx.x;
    int mt = blockIdx.y;                          // 0..15, 32 rows
    __shared__ unsigned short As[32 * 128];       // 8 KB
    __shared__ unsigned short Ws[128 * 128];      // 32 KB
    __shared__ float psum[2][2][16][2];           // [ch][rt][row][s|sq]
    int tid = threadIdx.x, lane = tid & 63, wv = tid >> 6;
    int l15 = lane & 15, quad = lane >> 4;
    int rt = wv >> 1, ch = wv & 1;

    floatx4 acc[4];
    for (int c4 = 0; c4 < 4; ++c4) acc[c4] = (floatx4){0.f, 0.f, 0.f, 0.f};
    size_t rowbase = (size_t)bp * 512 + mt * 32;

    for (int kc = 0; kc < 3; ++kc) {
        __syncthreads();
        for (int i = 0; i < 2; ++i) {             // As: 32x128
            int flat = i * 256 + tid;
            int row = flat >> 4, colg = (flat & 15) * 8;
            *(short8*)&As[row * 128 + colg] =
                *(const short8*)&att_ws[(rowbase + row) * 384 + kc * 128 + colg];
        }
        for (int i = 0; i < 8; ++i) {             // Ws: 128x128 slice of Wo
            int flat = i * 256 + tid;
            int row = flat >> 4, colg = (flat & 15) * 8;
            *(short8*)&Ws[row * 128 + colg] =
                *(const short8*)&Wob[(size_t)row * 384 + kc * 128 + colg];
        }
        __syncthreads();
        for (int c4 = 0; c4 < 4; ++c4) {
            int ct = ch * 4 + c4;
            for (int kk = 0; kk < 4; ++kk) {
                short8 a = *(const short8*)&As[(rt * 16 + l15) * 128 + kk * 32 + quad * 8];
                short8 b = *(const short8*)&Ws[(ct * 16 + l15) * 128 + kk * 32 + quad * 8];
                acc[c4] = __builtin_amdgcn_mfma_f32_16x16x32_bf16(a, b, acc[c4], 0, 0, 0);
            }
        }
    }

    // epilogue: residual; partial s/sq over this wave's 64 cols; cross-pair via LDS
    float vals[4][4], ssum[4], qsum[4];
    for (int i = 0; i < 4; ++i) {
        size_t grow = rowbase + rt * 16 + quad * 4 + i;
        float s = 0.f, sq = 0.f;
        for (int c4 = 0; c4 < 4; ++c4) {
            int col = (ch * 4 + c4) * 16 + l15;
            float v = acc[c4][i] + X[grow * 128 + col];
            vals[i][c4] = v;
            s += v; sq += v * v;
        }
        for (int d = 1; d < 16; d <<= 1) {
            s  += __shfl_xor(s, d, 64);
            sq += __shfl_xor(sq, d, 64);
        }
        ssum[i] = s; qsum[i] = sq;
        if (l15 == 0) {
            psum[ch][rt][quad * 4 + i][0] = s;
            psum[ch][rt][quad * 4 + i][1] = sq;
        }
    }
    __syncthreads();
    for (int i = 0; i < 4; ++i) {
        size_t grow = rowbase + rt * 16 + quad * 4 + i;
        float s  = ssum[i] + psum[ch ^ 1][rt][quad * 4 + i][0];
        float sq = qsum[i] + psum[ch ^ 1][rt][quad * 4 + i][1];
        float mu = s * (1.0f / 128.0f);
        float var = sq * (1.0f / 128.0f) - mu * mu;
        float rs = rsqrtf(var + 1e-5f);
        for (int c4 = 0; c4 < 4; ++c4) {
            int col = (ch * 4 + c4) * 16 + l15;
            out[grow * 128 + col] = (vals[i][c4] - mu) * rs * gamma[col] + beta[col];
        }
    }
}

// ---------------- K3b: out-projection, inline-cvt fallback (R8-proven) --------
__global__ __launch_bounds__(256) void k_oproj_cvt(
    const unsigned short* __restrict__ att_ws,
    const float* __restrict__ Wo,
    const float* __restrict__ X,
    const float* __restrict__ gamma,
    const float* __restrict__ beta,
    float* __restrict__ out)
{
    int bp = blockIdx.x;
    int mt = blockIdx.y;
    __shared__ unsigned short As[64 * 128];
    __shared__ unsigned short Ws[128 * 128];
    int tid = threadIdx.x, lane = tid & 63, wv = tid >> 6;
    int l15 = lane & 15, quad = lane >> 4;

    floatx4 acc[8];
    for (int ct = 0; ct < 8; ++ct) acc[ct] = (floatx4){0.f, 0.f, 0.f, 0.f};
    size_t rowbase = (size_t)bp * 512 + mt * 64;

    for (int kc = 0; kc < 3; ++kc) {
        __syncthreads();
        for (int i = 0; i < 4; ++i) {
            int flat = i * 256 + tid;
            int row = flat >> 4, colg = (flat & 15) * 8;
            *(short8*)&As[row * 128 + colg] =
                *(const short8*)&att_ws[(rowbase + row) * 384 + kc * 128 + colg];
        }
        for (int i = 0; i < 8; ++i) {
            int flat = i * 256 + tid;
            int row = flat >> 4, colg = (flat & 15) * 8;
            *(short8*)&Ws[row * 128 + colg] = cvt8(&Wo[(size_t)row * 384 + kc * 128 + colg]);
        }
        __syncthreads();
        for (int ct = 0; ct < 8; ++ct) {
            for (int kk = 0; kk < 4; ++kk) {
                short8 a = *(const short8*)&As[(wv * 16 + l15) * 128 + kk * 32 + quad * 8];
                short8 b = *(const short8*)&Ws[(ct * 16 + l15) * 128 + kk * 32 + quad * 8];
                acc[ct] = __builtin_amdgcn_mfma_f32_16x16x32_bf16(a, b, acc[ct], 0, 0, 0);
            }
        }
    }

    for (int i = 0; i < 4; ++i) {
        int lrow = wv * 16 + quad * 4 + i;
        size_t grow = rowbase + lrow;
        float vals[8];
        float s = 0.f, sq = 0.f;
        for (int ct = 0; ct < 8; ++ct) {
            int col = ct * 16 + l15;
            float v = acc[ct][i] + X[grow * 128 + col];
            vals[ct] = v;
            s += v; sq += v * v;
        }
        for (int d = 1; d < 16; d <<= 1) {
            s  += __shfl_xor(s, d, 64);
            sq += __shfl_xor(sq, d, 64);
        }
        float mu = s * (1.0f / 128.0f);
        float var = sq * (1.0f / 128.0f) - mu * mu;
        float rs = rsqrtf(var + 1e-5f);
        for (int ct = 0; ct < 8; ++ct) {
            int col = ct * 16 + l15;
            out[grow * 128 + col] = (vals[ct] - mu) * rs * gamma[col] + beta[col];
        }
    }
}

// ---------------- launcher ----------------
extern "C" void kernel_launch(void* const* d_in, const int* in_sizes, int n_in,
                              void* d_out, int out_size, void* d_ws, size_t ws_size,
                              hipStream_t stream) {
    const float* X     = (const float*)d_in[0];
    const float* TM    = (const float*)d_in[2];
    const float* Wq    = (const float*)d_in[3];
    const float* Wk    = (const float*)d_in[4];
    const float* Wv    = (const float*)d_in[5];
    const float* Wo    = (const float*)d_in[6];
    const float* gamma = (const float*)d_in[7];
    const float* beta  = (const float*)d_in[8];
    float* out = (float*)d_out;

    char* ws = (char*)d_ws;
    const size_t QKV1 = 2097152;             // elems per t per tensor
    const size_t QKV1B = QKV1 * 2;           // 4 MB

    if (ws_size >= WS_XL) {
        unsigned short* q3   = (unsigned short*)(ws);
        unsigned short* k3   = (unsigned short*)(ws + 3 * QKV1B);
        unsigned short* v3   = (unsigned short*)(ws + 6 * QKV1B);
        unsigned short* att  = (unsigned short*)(ws + 9 * QKV1B);
        unsigned short* Wb   = (unsigned short*)(ws + 50331648ull);
        unsigned short* Wob  = (unsigned short*)(ws + 50626560ull);
        unsigned short* tmTb = (unsigned short*)(ws + 50724864ull);
        k_prep<<<dim3(288), 256, 0, stream>>>(Wq, Wk, Wv, Wo, TM, Wb, Wob, tmTb);
        k_qkv2<<<dim3(32, 4, 9), 256, 0, stream>>>(X, Wb, q3, k3, v3);
        k_attn_t<<<dim3(4, 32, 12), 512, 0, stream>>>(q3, k3, v3, tmTb, att);
        k_oproj2<<<dim3(32, 16), 256, 0, stream>>>(att, Wob, X, gamma, beta, out);
    } else if (ws_size >= WS_BIG) {
        unsigned short* q3  = (unsigned short*)(ws);
        unsigned short* k3  = (unsigned short*)(ws + 3 * QKV1B);
        unsigned short* v3  = (unsigned short*)(ws + 6 * QKV1B);
        unsigned short* att = (unsigned short*)(ws + 9 * QKV1B);
        k_qkv_cvt<<<dim3(32, 4, 3), 256, 0, stream>>>(
            X, Wq, Wk, Wv, q3, k3, v3, 16384, (int)QKV1);
        k_attn_f32<<<dim3(4, 32, 12), 512, 0, stream>>>(q3, k3, v3, TM, att, (int)QKV1, 0);
        k_oproj_cvt<<<dim3(32, 8), 256, 0, stream>>>(att, Wo, X, gamma, beta, out);
    } else {
        unsigned short* q_ws   = (unsigned short*)(ws);
        unsigned short* k_ws   = (unsigned short*)(ws + QKV1B);
        unsigned short* v_ws   = (unsigned short*)(ws + 2 * QKV1B);
        unsigned short* att_ws = (unsigned short*)(ws + 3 * QKV1B);
        const int tsel[3] = {0, 1, 3};
        for (int t = 0; t < 3; ++t) {
            k_qkv_cvt<<<dim3(32, 4, 1), 256, 0, stream>>>(
                X, Wq + (size_t)t * 16384, Wk + (size_t)t * 16384, Wv + (size_t)t * 16384,
                q_ws, k_ws, v_ws, 0, 0);
            k_attn_f32<<<dim3(4, 32, 4), 512, 0, stream>>>(
                q_ws, k_ws, v_ws, TM + (size_t)tsel[t] * 262144, att_ws, 0, t * 128);
        }
        k_oproj_cvt<<<dim3(32, 8), 256, 0, stream>>>(att_ws, Wo, X, gamma, beta, out);
    }
}

// Round 12
// 187.666 us; speedup vs baseline: 1.1650x; 1.1650x over previous
//
#include <hip/hip_runtime.h>

// ---------------- problem constants ----------------
// B*P=32, N=512, D=128, H=4, DK=32, T=3 (tm {0,1,3}; tsel(t)=t+(t>>1))
// Inputs f32, OUTPUT f32. XL path (ws >= 54.9MB) confirmed in R10.
// R11 post-mortem: tmT bf16 attn REGRESSED (74->102us) -> reverted to R10 attn.
// qkv/oproj grid splits were neutral -> reverted. New: k_qkv stores were 576
// scalar 2B global stores per wave (the real "others" bottleneck) -> per-wave
// LDS repack + 24 fully-coalesced 1KB vector stores.

typedef __attribute__((ext_vector_type(8))) short  short8;
typedef __attribute__((ext_vector_type(4))) float  floatx4;

#define WS_BIG   50331648ull                  // q3/k3/v3 (37.7MB) + att (12.6MB)
#define WS_XL    54919168ull                  // + Xb 4MB + Wb 288KB + Wob 96KB
#define QSCALE   0.25503486f                  // (1/sqrt(32)) * log2(e)

__device__ __forceinline__ float b2f(unsigned short u) {
    union { unsigned int i; float f; } v; v.i = ((unsigned int)u) << 16; return v.f;
}
__device__ __forceinline__ unsigned short f2b(float f) {
    union { float f; unsigned int i; } v; v.f = f;
    unsigned int x = v.i;
    return (unsigned short)((x + 0x7fffu + ((x >> 16) & 1u)) >> 16);
}
__device__ __forceinline__ short8 cvt8(const float* p) {
    floatx4 a = *(const floatx4*)p;
    floatx4 b = *(const floatx4*)(p + 4);
    short8 r;
    r[0] = (short)f2b(a[0]); r[1] = (short)f2b(a[1]);
    r[2] = (short)f2b(a[2]); r[3] = (short)f2b(a[3]);
    r[4] = (short)f2b(b[0]); r[5] = (short)f2b(b[1]);
    r[6] = (short)f2b(b[2]); r[7] = (short)f2b(b[3]);
    return r;
}

// ---------------- K0: one-time f32->bf16 conversion of X, Wq/Wk/Wv, Wo --------
// grid 1120 x 256, 8 elems/thread.
__global__ __launch_bounds__(256) void k_prep(
    const float* __restrict__ X,  const float* __restrict__ Wq,
    const float* __restrict__ Wk, const float* __restrict__ Wv,
    const float* __restrict__ Wo,
    unsigned short* __restrict__ Xb, unsigned short* __restrict__ Wb,
    unsigned short* __restrict__ Wob)
{
    size_t i = ((size_t)blockIdx.x * 256 + threadIdx.x) * 8;
    const float* src; unsigned short* dst; size_t off;
    if      (i < 2097152) { src = X;  dst = Xb;          off = i; }
    else if (i < 2146304) { src = Wq; dst = Wb;          off = i - 2097152; }
    else if (i < 2195456) { src = Wk; dst = Wb + 49152;  off = i - 2146304; }
    else if (i < 2244608) { src = Wv; dst = Wb + 98304;  off = i - 2195456; }
    else                  { src = Wo; dst = Wob;         off = i - 2244608; }
    *(short8*)&dst[off] = cvt8(&src[off]);
}

// ---------------- K1a: QKV projection, LDS-repacked coalesced stores ----------
// grid (bp=32, mt=4, tz=3). LDS = Xs 32KB + Cs 32KB = 64KB (allowed, R2 evidence).
// Per wave: accs -> per-wave Cs scratch (b16, XOR-swizzled: quads 2-way = free),
// then 8 x 1KB fully-coalesced short8 stores per qkv (was 192 scalar 2B stores).
__global__ __launch_bounds__(256) void k_qkv_pre(
    const unsigned short* __restrict__ Xb,   // [32][512][128] bf16
    const unsigned short* __restrict__ Wb,   // [3 qkv][3 t][128][128] bf16
    unsigned short* __restrict__ q_ws,
    unsigned short* __restrict__ k_ws,
    unsigned short* __restrict__ v_ws)
{
    int bp = blockIdx.x, mt = blockIdx.y, tz = blockIdx.z;
    __shared__ unsigned short Xs[128 * 128];     // 32 KB
    __shared__ unsigned short Cs[4][32 * 128];   // 32 KB (8KB per wave)
    int tid = threadIdx.x;
    int lane = tid & 63, wv = tid >> 6;
    int l15 = lane & 15, quad = lane >> 4;

    const unsigned short* Xbase = Xb + ((size_t)bp * 512 + mt * 128) * 128;
    for (int i = 0; i < 8; ++i) {
        int e = (i * 256 + tid) * 8;
        *(short8*)&Xs[e] = *(const short8*)&Xbase[e];
    }
    __syncthreads();

    unsigned short* Osel[3] = { q_ws, k_ws, v_ws };
    int rt0 = wv * 2, rt1 = wv * 2 + 1;

    for (int qkv = 0; qkv < 3; ++qkv) {
        const unsigned short* Wt = Wb + qkv * 49152 + tz * 16384;
        // wave's 32-row slab base: rows mt*128 + wv*32
        unsigned short* Ob = Osel[qkv] + (size_t)tz * 2097152
                           + ((size_t)bp * 512 + mt * 128 + wv * 32) * 128;
        float sc = (qkv == 0) ? QSCALE : 1.0f;

        for (int ct = 0; ct < 8; ++ct) {
            short8 bfr[4];
            for (int kk = 0; kk < 4; ++kk)
                bfr[kk] = *(const short8*)&Wt[(size_t)(ct * 16 + l15) * 128 + kk * 32 + quad * 8];
            floatx4 acc0 = {0.f, 0.f, 0.f, 0.f};
            floatx4 acc1 = {0.f, 0.f, 0.f, 0.f};
            for (int kk = 0; kk < 4; ++kk) {
                short8 a0 = *(const short8*)&Xs[(rt0 * 16 + l15) * 128 + kk * 32 + quad * 8];
                short8 a1 = *(const short8*)&Xs[(rt1 * 16 + l15) * 128 + kk * 32 + quad * 8];
                acc0 = __builtin_amdgcn_mfma_f32_16x16x32_bf16(a0, bfr[kk], acc0, 0, 0, 0);
                acc1 = __builtin_amdgcn_mfma_f32_16x16x32_bf16(a1, bfr[kk], acc1, 0, 0, 0);
            }
            #pragma unroll
            for (int i = 0; i < 4; ++i) {
                int row = quad * 4 + i;                  // 0..15 (acc0); +16 acc1
                int swz = (row & 7) << 4;                // same for row and row+16
                int col = (ct * 16 + l15) ^ swz;
                Cs[wv][row * 128 + col]        = f2b(acc0[i] * sc);
                Cs[wv][(16 + row) * 128 + col] = f2b(acc1[i] * sc);
            }
        }
        // per-wave repack (no barrier needed): 8 x 1KB coalesced stores
        #pragma unroll
        for (int j = 0; j < 8; ++j) {
            int flat = j * 64 + lane;                    // 0..511
            int r = flat >> 4;                           // 0..31
            int cg = (flat & 15) * 8;                    // 0..120
            int cgs = cg ^ ((r & 7) << 4);               // physical (swizzled) col
            *(short8*)&Ob[(size_t)r * 128 + cg] = *(const short8*)&Cs[wv][r * 128 + cgs];
        }
    }
}

// ---------------- K1b: QKV projection, inline-cvt fallback (R8-proven) --------
__global__ __launch_bounds__(256) void k_qkv_cvt(
    const float* __restrict__ X,
    const float* __restrict__ Wq, const float* __restrict__ Wk,
    const float* __restrict__ Wv,
    unsigned short* __restrict__ q_ws, unsigned short* __restrict__ k_ws,
    unsigned short* __restrict__ v_ws,
    int wstride, int ostride)
{
    int bp = blockIdx.x, mt = blockIdx.y, tz = blockIdx.z;
    __shared__ unsigned short Xs[128 * 128];
    int tid = threadIdx.x;
    int lane = tid & 63, wv = tid >> 6;
    int l15 = lane & 15, quad = lane >> 4;

    const float* Xbase = X + ((size_t)bp * 512 + mt * 128) * 128;
    for (int i = 0; i < 8; ++i) {
        int e = (i * 256 + tid) * 8;
        *(short8*)&Xs[e] = cvt8(&Xbase[e]);
    }
    __syncthreads();

    size_t woff = (size_t)tz * wstride;
    size_t ooff = (size_t)tz * ostride;
    const float* Wsel[3] = { Wq + woff, Wk + woff, Wv + woff };
    unsigned short* Osel[3] = { q_ws + ooff, k_ws + ooff, v_ws + ooff };

    for (int qkv = 0; qkv < 3; ++qkv) {
        const float* Wt = Wsel[qkv];
        unsigned short* Ob = Osel[qkv] + ((size_t)bp * 512 + mt * 128) * 128;
        float sc = (qkv == 0) ? QSCALE : 1.0f;
        for (int ct = 0; ct < 8; ++ct) {
            short8 bfr[4];
            for (int kk = 0; kk < 4; ++kk)
                bfr[kk] = cvt8(&Wt[(size_t)(ct * 16 + l15) * 128 + kk * 32 + quad * 8]);
            floatx4 acc0 = {0.f, 0.f, 0.f, 0.f};
            floatx4 acc1 = {0.f, 0.f, 0.f, 0.f};
            int rt0 = wv * 2, rt1 = wv * 2 + 1;
            for (int kk = 0; kk < 4; ++kk) {
                short8 a0 = *(const short8*)&Xs[(rt0 * 16 + l15) * 128 + kk * 32 + quad * 8];
                short8 a1 = *(const short8*)&Xs[(rt1 * 16 + l15) * 128 + kk * 32 + quad * 8];
                acc0 = __builtin_amdgcn_mfma_f32_16x16x32_bf16(a0, bfr[kk], acc0, 0, 0, 0);
                acc1 = __builtin_amdgcn_mfma_f32_16x16x32_bf16(a1, bfr[kk], acc1, 0, 0, 0);
            }
            int col = ct * 16 + l15;
            for (int i = 0; i < 4; ++i) {
                Ob[(size_t)(rt0 * 16 + quad * 4 + i) * 128 + col] = f2b(acc0[i] * sc);
                Ob[(size_t)(rt1 * 16 + quad * 4 + i) * 128 + col] = f2b(acc1[i] * sc);
            }
        }
    }
}

// ---------------- K2: dense MFMA masked attention (R10-proven, f32 tm) --------
__global__ __launch_bounds__(512) void k_attn(
    const unsigned short* __restrict__ q_ws,   // bf16, pre-scaled by QSCALE
    const unsigned short* __restrict__ k_ws,
    const unsigned short* __restrict__ v_ws,
    const float* __restrict__ tm,
    unsigned short* __restrict__ att_ws,       // [32][512][384] bf16
    int qkv_stride, int toff0)
{
    int nc = blockIdx.x;
    int bp = blockIdx.y;
    int z  = blockIdx.z;
    int t = z >> 2, h = z & 3;
    size_t qoff = (size_t)t * (size_t)qkv_stride;
    const float* tmt = tm + (size_t)(t + (t >> 1)) * 262144;
    int toff = toff0 + t * 128;

    __shared__ unsigned short Vt[32][516];
    __shared__ unsigned short Ps[8][16][72];

    int tid = threadIdx.x, lane = tid & 63, wv = tid >> 6;
    int l15 = lane & 15, quad = lane >> 4;

    {
        const unsigned short* vp = v_ws + qoff + ((size_t)bp * 512 + tid) * 128 + h * 32;
        short8 a = *(const short8*)vp;
        short8 b = *(const short8*)(vp + 8);
        short8 c = *(const short8*)(vp + 16);
        short8 d = *(const short8*)(vp + 24);
        #pragma unroll
        for (int j = 0; j < 8; ++j) {
            Vt[j][tid]      = (unsigned short)a[j];
            Vt[8 + j][tid]  = (unsigned short)b[j];
            Vt[16 + j][tid] = (unsigned short)c[j];
            Vt[24 + j][tid] = (unsigned short)d[j];
        }
    }
    int n0 = nc * 128 + wv * 16;
    short8 qf = *(const short8*)&q_ws[qoff +
        ((size_t)bp * 512 + n0 + l15) * 128 + h * 32 + quad * 8];
    __syncthreads();

    const unsigned short* Kb = k_ws + qoff + (size_t)bp * 512 * 128 + h * 32;
    floatx4 O0 = {0.f, 0.f, 0.f, 0.f};
    floatx4 O1 = {0.f, 0.f, 0.f, 0.f};
    float za[4] = {0.f, 0.f, 0.f, 0.f};
    const floatx4 zero4 = {0.f, 0.f, 0.f, 0.f};

    for (int c = 0; c < 8; ++c) {
        int mb = c * 64;
        short8 kf0 = *(const short8*)&Kb[(size_t)(mb +  0 + l15) * 128 + quad * 8];
        short8 kf1 = *(const short8*)&Kb[(size_t)(mb + 16 + l15) * 128 + quad * 8];
        short8 kf2 = *(const short8*)&Kb[(size_t)(mb + 32 + l15) * 128 + quad * 8];
        short8 kf3 = *(const short8*)&Kb[(size_t)(mb + 48 + l15) * 128 + quad * 8];
        floatx4 S[4];
        S[0] = __builtin_amdgcn_mfma_f32_16x16x32_bf16(qf, kf0, zero4, 0, 0, 0);
        S[1] = __builtin_amdgcn_mfma_f32_16x16x32_bf16(qf, kf1, zero4, 0, 0, 0);
        S[2] = __builtin_amdgcn_mfma_f32_16x16x32_bf16(qf, kf2, zero4, 0, 0, 0);
        S[3] = __builtin_amdgcn_mfma_f32_16x16x32_bf16(qf, kf3, zero4, 0, 0, 0);

        #pragma unroll
        for (int ti = 0; ti < 4; ++ti) {
            int m = mb + ti * 16 + l15;
            #pragma unroll
            for (int i = 0; i < 4; ++i) {
                float tmv = tmt[(size_t)(n0 + quad * 4 + i) * 512 + m];
                float e = __builtin_amdgcn_exp2f(S[ti][i]);
                bool on = (tmv != 0.0f);
                za[i] += on ? e : 0.0f;
                float w = on ? e * tmv : 0.0f;
                Ps[wv][quad * 4 + i][ti * 16 + l15] = f2b(w);
            }
        }
        #pragma unroll
        for (int kc = 0; kc < 2; ++kc) {
            short8 pa  = *(const short8*)&Ps[wv][l15][kc * 32 + quad * 8];
            short8 vb0 = *(const short8*)&Vt[l15][mb + kc * 32 + quad * 8];
            short8 vb1 = *(const short8*)&Vt[16 + l15][mb + kc * 32 + quad * 8];
            O0 = __builtin_amdgcn_mfma_f32_16x16x32_bf16(pa, vb0, O0, 0, 0, 0);
            O1 = __builtin_amdgcn_mfma_f32_16x16x32_bf16(pa, vb1, O1, 0, 0, 0);
        }
    }

    #pragma unroll
    for (int d = 1; d < 16; d <<= 1) {
        #pragma unroll
        for (int i = 0; i < 4; ++i) za[i] += __shfl_xor(za[i], d, 64);
    }
    #pragma unroll
    for (int i = 0; i < 4; ++i) {
        float rz = 1.0f / za[i];
        size_t row = (size_t)bp * 512 + n0 + quad * 4 + i;
        att_ws[row * 384 + toff + h * 32 + l15]      = f2b(O0[i] * rz);
        att_ws[row * 384 + toff + h * 32 + 16 + l15] = f2b(O1[i] * rz);
    }
}

// ---------------- K3a: out-projection from pre-converted Wo (R10-proven) ------
__global__ __launch_bounds__(256) void k_oproj_pre(
    const unsigned short* __restrict__ att_ws,   // [32][512][384] bf16
    const unsigned short* __restrict__ Wob,      // [128][384] bf16
    const float* __restrict__ X,
    const float* __restrict__ gamma,
    const float* __restrict__ beta,
    float* __restrict__ out)
{
    int bp = blockIdx.x;
    int mt = blockIdx.y;
    __shared__ unsigned short As[64 * 128];
    __shared__ unsigned short Ws[128 * 128];
    int tid = threadIdx.x, lane = tid & 63, wv = tid >> 6;
    int l15 = lane & 15, quad = lane >> 4;

    floatx4 acc[8];
    for (int ct = 0; ct < 8; ++ct) acc[ct] = (floatx4){0.f, 0.f, 0.f, 0.f};
    size_t rowbase = (size_t)bp * 512 + mt * 64;

    for (int kc = 0; kc < 3; ++kc) {
        __syncthreads();
        for (int i = 0; i < 4; ++i) {
            int flat = i * 256 + tid;
            int row = flat >> 4, colg = (flat & 15) * 8;
            *(short8*)&As[row * 128 + colg] =
                *(const short8*)&att_ws[(rowbase + row) * 384 + kc * 128 + colg];
        }
        for (int i = 0; i < 8; ++i) {
            int flat = i * 256 + tid;
            int row = flat >> 4, colg = (flat & 15) * 8;
            *(short8*)&Ws[row * 128 + colg] =
                *(const short8*)&Wob[(size_t)row * 384 + kc * 128 + colg];
        }
        __syncthreads();
        for (int ct = 0; ct < 8; ++ct) {
            for (int kk = 0; kk < 4; ++kk) {
                short8 a = *(const short8*)&As[(wv * 16 + l15) * 128 + kk * 32 + quad * 8];
                short8 b = *(const short8*)&Ws[(ct * 16 + l15) * 128 + kk * 32 + quad * 8];
                acc[ct] = __builtin_amdgcn_mfma_f32_16x16x32_bf16(a, b, acc[ct], 0, 0, 0);
            }
        }
    }

    for (int i = 0; i < 4; ++i) {
        int lrow = wv * 16 + quad * 4 + i;
        size_t grow = rowbase + lrow;
        float vals[8];
        float s = 0.f, sq = 0.f;
        for (int ct = 0; ct < 8; ++ct) {
            int col = ct * 16 + l15;
            float v = acc[ct][i] + X[grow * 128 + col];
            vals[ct] = v;
            s += v; sq += v * v;
        }
        for (int d = 1; d < 16; d <<= 1) {
            s  += __shfl_xor(s, d, 64);
            sq += __shfl_xor(sq, d, 64);
        }
        float mu = s * (1.0f / 128.0f);
        float var = sq * (1.0f / 128.0f) - mu * mu;
        float rs = rsqrtf(var + 1e-5f);
        for (int ct = 0; ct < 8; ++ct) {
            int col = ct * 16 + l15;
            out[grow * 128 + col] = (vals[ct] - mu) * rs * gamma[col] + beta[col];
        }
    }
}

// ---------------- K3b: out-projection, inline-cvt fallback (R8-proven) --------
__global__ __launch_bounds__(256) void k_oproj_cvt(
    const unsigned short* __restrict__ att_ws,
    const float* __restrict__ Wo,
    const float* __restrict__ X,
    const float* __restrict__ gamma,
    const float* __restrict__ beta,
    float* __restrict__ out)
{
    int bp = blockIdx.x;
    int mt = blockIdx.y;
    __shared__ unsigned short As[64 * 128];
    __shared__ unsigned short Ws[128 * 128];
    int tid = threadIdx.x, lane = tid & 63, wv = tid >> 6;
    int l15 = lane & 15, quad = lane >> 4;

    floatx4 acc[8];
    for (int ct = 0; ct < 8; ++ct) acc[ct] = (floatx4){0.f, 0.f, 0.f, 0.f};
    size_t rowbase = (size_t)bp * 512 + mt * 64;

    for (int kc = 0; kc < 3; ++kc) {
        __syncthreads();
        for (int i = 0; i < 4; ++i) {
            int flat = i * 256 + tid;
            int row = flat >> 4, colg = (flat & 15) * 8;
            *(short8*)&As[row * 128 + colg] =
                *(const short8*)&att_ws[(rowbase + row) * 384 + kc * 128 + colg];
        }
        for (int i = 0; i < 8; ++i) {
            int flat = i * 256 + tid;
            int row = flat >> 4, colg = (flat & 15) * 8;
            *(short8*)&Ws[row * 128 + colg] = cvt8(&Wo[(size_t)row * 384 + kc * 128 + colg]);
        }
        __syncthreads();
        for (int ct = 0; ct < 8; ++ct) {
            for (int kk = 0; kk < 4; ++kk) {
                short8 a = *(const short8*)&As[(wv * 16 + l15) * 128 + kk * 32 + quad * 8];
                short8 b = *(const short8*)&Ws[(ct * 16 + l15) * 128 + kk * 32 + quad * 8];
                acc[ct] = __builtin_amdgcn_mfma_f32_16x16x32_bf16(a, b, acc[ct], 0, 0, 0);
            }
        }
    }

    for (int i = 0; i < 4; ++i) {
        int lrow = wv * 16 + quad * 4 + i;
        size_t grow = rowbase + lrow;
        float vals[8];
        float s = 0.f, sq = 0.f;
        for (int ct = 0; ct < 8; ++ct) {
            int col = ct * 16 + l15;
            float v = acc[ct][i] + X[grow * 128 + col];
            vals[ct] = v;
            s += v; sq += v * v;
        }
        for (int d = 1; d < 16; d <<= 1) {
            s  += __shfl_xor(s, d, 64);
            sq += __shfl_xor(sq, d, 64);
        }
        float mu = s * (1.0f / 128.0f);
        float var = sq * (1.0f / 128.0f) - mu * mu;
        float rs = rsqrtf(var + 1e-5f);
        for (int ct = 0; ct < 8; ++ct) {
            int col = ct * 16 + l15;
            out[grow * 128 + col] = (vals[ct] - mu) * rs * gamma[col] + beta[col];
        }
    }
}

// ---------------- launcher ----------------
extern "C" void kernel_launch(void* const* d_in, const int* in_sizes, int n_in,
                              void* d_out, int out_size, void* d_ws, size_t ws_size,
                              hipStream_t stream) {
    const float* X     = (const float*)d_in[0];
    const float* TM    = (const float*)d_in[2];
    const float* Wq    = (const float*)d_in[3];
    const float* Wk    = (const float*)d_in[4];
    const float* Wv    = (const float*)d_in[5];
    const float* Wo    = (const float*)d_in[6];
    const float* gamma = (const float*)d_in[7];
    const float* beta  = (const float*)d_in[8];
    float* out = (float*)d_out;

    char* ws = (char*)d_ws;
    const size_t QKV1 = 2097152;             // elems per t per tensor
    const size_t QKV1B = QKV1 * 2;           // 4 MB

    if (ws_size >= WS_XL) {
        // XL path (confirmed running): prep + 3 compute kernels
        unsigned short* q3  = (unsigned short*)(ws);
        unsigned short* k3  = (unsigned short*)(ws + 3 * QKV1B);
        unsigned short* v3  = (unsigned short*)(ws + 6 * QKV1B);
        unsigned short* att = (unsigned short*)(ws + 9 * QKV1B);
        unsigned short* Xb  = (unsigned short*)(ws + 50331648ull);
        unsigned short* Wb  = (unsigned short*)(ws + 54525952ull);
        unsigned short* Wob = (unsigned short*)(ws + 54820864ull);
        k_prep<<<dim3(1120), 256, 0, stream>>>(X, Wq, Wk, Wv, Wo, Xb, Wb, Wob);
        k_qkv_pre<<<dim3(32, 4, 3), 256, 0, stream>>>(Xb, Wb, q3, k3, v3);
        k_attn<<<dim3(4, 32, 12), 512, 0, stream>>>(q3, k3, v3, TM, att, (int)QKV1, 0);
        k_oproj_pre<<<dim3(32, 8), 256, 0, stream>>>(att, Wob, X, gamma, beta, out);
    } else if (ws_size >= WS_BIG) {
        unsigned short* q3  = (unsigned short*)(ws);
        unsigned short* k3  = (unsigned short*)(ws + 3 * QKV1B);
        unsigned short* v3  = (unsigned short*)(ws + 6 * QKV1B);
        unsigned short* att = (unsigned short*)(ws + 9 * QKV1B);
        k_qkv_cvt<<<dim3(32, 4, 3), 256, 0, stream>>>(
            X, Wq, Wk, Wv, q3, k3, v3, 16384, (int)QKV1);
        k_attn<<<dim3(4, 32, 12), 512, 0, stream>>>(q3, k3, v3, TM, att, (int)QKV1, 0);
        k_oproj_cvt<<<dim3(32, 8), 256, 0, stream>>>(att, Wo, X, gamma, beta, out);
    } else {
        unsigned short* q_ws   = (unsigned short*)(ws);
        unsigned short* k_ws   = (unsigned short*)(ws + QKV1B);
        unsigned short* v_ws   = (unsigned short*)(ws + 2 * QKV1B);
        unsigned short* att_ws = (unsigned short*)(ws + 3 * QKV1B);
        const int tsel[3] = {0, 1, 3};
        for (int t = 0; t < 3; ++t) {
            k_qkv_cvt<<<dim3(32, 4, 1), 256, 0, stream>>>(
                X, Wq + (size_t)t * 16384, Wk + (size_t)t * 16384, Wv + (size_t)t * 16384,
                q_ws, k_ws, v_ws, 0, 0);
            k_attn<<<dim3(4, 32, 4), 512, 0, stream>>>(
                q_ws, k_ws, v_ws, TM + (size_t)tsel[t] * 262144, att_ws, 0, t * 128);
        }
        k_oproj_cvt<<<dim3(32, 8), 256, 0, stream>>>(att_ws, Wo, X, gamma, beta, out);
    }
}

// Round 13
// 171.432 us; speedup vs baseline: 1.2753x; 1.0947x over previous
//
#include <hip/hip_runtime.h>

// ---------------- problem constants ----------------
// B*P=32, N=512, D=128, H=4, DK=32, T=3 (tm {0,1,3}; tsel(t)=t+(t>>1))
// Inputs f32, OUTPUT f32. XL path (ws >= 54.9MB) confirmed.
// R12: 187.7us; k_attn 74us with FETCH 58.6MB (~21MB redundancy from 4x nc
// blocks re-staging V / re-fetching K). R13: nc-merge x2 -> 768 blocks
// (exactly 3/CU), each wave runs 2 Q-strips per staged K chunk; P-loop micro:
// no w-cndmask, half-up bit rounding. k_prep/k_qkv/k_oproj unchanged (proven).

typedef __attribute__((ext_vector_type(8))) short  short8;
typedef __attribute__((ext_vector_type(4))) float  floatx4;

#define WS_BIG   50331648ull                  // q3/k3/v3 (37.7MB) + att (12.6MB)
#define WS_XL    54919168ull                  // + Xb 4MB + Wb 288KB + Wob 96KB
#define QSCALE   0.25503486f                  // (1/sqrt(32)) * log2(e)

__device__ __forceinline__ float b2f(unsigned short u) {
    union { unsigned int i; float f; } v; v.i = ((unsigned int)u) << 16; return v.f;
}
__device__ __forceinline__ unsigned short f2b(float f) {
    union { float f; unsigned int i; } v; v.f = f;
    unsigned int x = v.i;
    return (unsigned short)((x + 0x7fffu + ((x >> 16) & 1u)) >> 16);
}
__device__ __forceinline__ unsigned int fbits(float f) {
    union { float f; unsigned int i; } v; v.f = f; return v.i;
}
__device__ __forceinline__ short8 cvt8(const float* p) {
    floatx4 a = *(const floatx4*)p;
    floatx4 b = *(const floatx4*)(p + 4);
    short8 r;
    r[0] = (short)f2b(a[0]); r[1] = (short)f2b(a[1]);
    r[2] = (short)f2b(a[2]); r[3] = (short)f2b(a[3]);
    r[4] = (short)f2b(b[0]); r[5] = (short)f2b(b[1]);
    r[6] = (short)f2b(b[2]); r[7] = (short)f2b(b[3]);
    return r;
}

// ---------------- K0: one-time f32->bf16 conversion of X, Wq/Wk/Wv, Wo --------
__global__ __launch_bounds__(256) void k_prep(
    const float* __restrict__ X,  const float* __restrict__ Wq,
    const float* __restrict__ Wk, const float* __restrict__ Wv,
    const float* __restrict__ Wo,
    unsigned short* __restrict__ Xb, unsigned short* __restrict__ Wb,
    unsigned short* __restrict__ Wob)
{
    size_t i = ((size_t)blockIdx.x * 256 + threadIdx.x) * 8;
    const float* src; unsigned short* dst; size_t off;
    if      (i < 2097152) { src = X;  dst = Xb;          off = i; }
    else if (i < 2146304) { src = Wq; dst = Wb;          off = i - 2097152; }
    else if (i < 2195456) { src = Wk; dst = Wb + 49152;  off = i - 2146304; }
    else if (i < 2244608) { src = Wv; dst = Wb + 98304;  off = i - 2195456; }
    else                  { src = Wo; dst = Wob;         off = i - 2244608; }
    *(short8*)&dst[off] = cvt8(&src[off]);
}

// ---------------- K1a: QKV projection (R12-proven, LDS-repacked stores) -------
__global__ __launch_bounds__(256) void k_qkv_pre(
    const unsigned short* __restrict__ Xb,   // [32][512][128] bf16
    const unsigned short* __restrict__ Wb,   // [3 qkv][3 t][128][128] bf16
    unsigned short* __restrict__ q_ws,
    unsigned short* __restrict__ k_ws,
    unsigned short* __restrict__ v_ws)
{
    int bp = blockIdx.x, mt = blockIdx.y, tz = blockIdx.z;
    __shared__ unsigned short Xs[128 * 128];     // 32 KB
    __shared__ unsigned short Cs[4][32 * 128];   // 32 KB (8KB per wave)
    int tid = threadIdx.x;
    int lane = tid & 63, wv = tid >> 6;
    int l15 = lane & 15, quad = lane >> 4;

    const unsigned short* Xbase = Xb + ((size_t)bp * 512 + mt * 128) * 128;
    for (int i = 0; i < 8; ++i) {
        int e = (i * 256 + tid) * 8;
        *(short8*)&Xs[e] = *(const short8*)&Xbase[e];
    }
    __syncthreads();

    unsigned short* Osel[3] = { q_ws, k_ws, v_ws };
    int rt0 = wv * 2, rt1 = wv * 2 + 1;

    for (int qkv = 0; qkv < 3; ++qkv) {
        const unsigned short* Wt = Wb + qkv * 49152 + tz * 16384;
        unsigned short* Ob = Osel[qkv] + (size_t)tz * 2097152
                           + ((size_t)bp * 512 + mt * 128 + wv * 32) * 128;
        float sc = (qkv == 0) ? QSCALE : 1.0f;

        for (int ct = 0; ct < 8; ++ct) {
            short8 bfr[4];
            for (int kk = 0; kk < 4; ++kk)
                bfr[kk] = *(const short8*)&Wt[(size_t)(ct * 16 + l15) * 128 + kk * 32 + quad * 8];
            floatx4 acc0 = {0.f, 0.f, 0.f, 0.f};
            floatx4 acc1 = {0.f, 0.f, 0.f, 0.f};
            for (int kk = 0; kk < 4; ++kk) {
                short8 a0 = *(const short8*)&Xs[(rt0 * 16 + l15) * 128 + kk * 32 + quad * 8];
                short8 a1 = *(const short8*)&Xs[(rt1 * 16 + l15) * 128 + kk * 32 + quad * 8];
                acc0 = __builtin_amdgcn_mfma_f32_16x16x32_bf16(a0, bfr[kk], acc0, 0, 0, 0);
                acc1 = __builtin_amdgcn_mfma_f32_16x16x32_bf16(a1, bfr[kk], acc1, 0, 0, 0);
            }
            #pragma unroll
            for (int i = 0; i < 4; ++i) {
                int row = quad * 4 + i;
                int swz = (row & 7) << 4;
                int col = (ct * 16 + l15) ^ swz;
                Cs[wv][row * 128 + col]        = f2b(acc0[i] * sc);
                Cs[wv][(16 + row) * 128 + col] = f2b(acc1[i] * sc);
            }
        }
        #pragma unroll
        for (int j = 0; j < 8; ++j) {
            int flat = j * 64 + lane;
            int r = flat >> 4;
            int cg = (flat & 15) * 8;
            int cgs = cg ^ ((r & 7) << 4);
            *(short8*)&Ob[(size_t)r * 128 + cg] = *(const short8*)&Cs[wv][r * 128 + cgs];
        }
    }
}

// ---------------- K1b: QKV projection, inline-cvt fallback --------------------
__global__ __launch_bounds__(256) void k_qkv_cvt(
    const float* __restrict__ X,
    const float* __restrict__ Wq, const float* __restrict__ Wk,
    const float* __restrict__ Wv,
    unsigned short* __restrict__ q_ws, unsigned short* __restrict__ k_ws,
    unsigned short* __restrict__ v_ws,
    int wstride, int ostride)
{
    int bp = blockIdx.x, mt = blockIdx.y, tz = blockIdx.z;
    __shared__ unsigned short Xs[128 * 128];
    int tid = threadIdx.x;
    int lane = tid & 63, wv = tid >> 6;
    int l15 = lane & 15, quad = lane >> 4;

    const float* Xbase = X + ((size_t)bp * 512 + mt * 128) * 128;
    for (int i = 0; i < 8; ++i) {
        int e = (i * 256 + tid) * 8;
        *(short8*)&Xs[e] = cvt8(&Xbase[e]);
    }
    __syncthreads();

    size_t woff = (size_t)tz * wstride;
    size_t ooff = (size_t)tz * ostride;
    const float* Wsel[3] = { Wq + woff, Wk + woff, Wv + woff };
    unsigned short* Osel[3] = { q_ws + ooff, k_ws + ooff, v_ws + ooff };

    for (int qkv = 0; qkv < 3; ++qkv) {
        const float* Wt = Wsel[qkv];
        unsigned short* Ob = Osel[qkv] + ((size_t)bp * 512 + mt * 128) * 128;
        float sc = (qkv == 0) ? QSCALE : 1.0f;
        for (int ct = 0; ct < 8; ++ct) {
            short8 bfr[4];
            for (int kk = 0; kk < 4; ++kk)
                bfr[kk] = cvt8(&Wt[(size_t)(ct * 16 + l15) * 128 + kk * 32 + quad * 8]);
            floatx4 acc0 = {0.f, 0.f, 0.f, 0.f};
            floatx4 acc1 = {0.f, 0.f, 0.f, 0.f};
            int rt0 = wv * 2, rt1 = wv * 2 + 1;
            for (int kk = 0; kk < 4; ++kk) {
                short8 a0 = *(const short8*)&Xs[(rt0 * 16 + l15) * 128 + kk * 32 + quad * 8];
                short8 a1 = *(const short8*)&Xs[(rt1 * 16 + l15) * 128 + kk * 32 + quad * 8];
                acc0 = __builtin_amdgcn_mfma_f32_16x16x32_bf16(a0, bfr[kk], acc0, 0, 0, 0);
                acc1 = __builtin_amdgcn_mfma_f32_16x16x32_bf16(a1, bfr[kk], acc1, 0, 0, 0);
            }
            int col = ct * 16 + l15;
            for (int i = 0; i < 4; ++i) {
                Ob[(size_t)(rt0 * 16 + quad * 4 + i) * 128 + col] = f2b(acc0[i] * sc);
                Ob[(size_t)(rt1 * 16 + quad * 4 + i) * 128 + col] = f2b(acc1[i] * sc);
            }
        }
    }
}

// ---------------- K2: dense MFMA attention, 2 strips per wave (nc-merge x2) ---
// grid (nc2=2, bp=32, z=t*4+h) = 768 blocks = exactly 3/CU (52KB LDS allows 3).
// Wave wv handles strips n0 = nc2*256 + wv*16 and n0+128 against each staged
// K chunk: K fetch /2, V staging /2, 2 independent exp chains for ILP.
__global__ __launch_bounds__(512) void k_attn2(
    const unsigned short* __restrict__ q_ws,   // bf16, pre-scaled by QSCALE
    const unsigned short* __restrict__ k_ws,
    const unsigned short* __restrict__ v_ws,
    const float* __restrict__ tm,
    unsigned short* __restrict__ att_ws,       // [32][512][384] bf16
    int qkv_stride, int toff0)
{
    int nc2 = blockIdx.x;
    int bp = blockIdx.y;
    int z  = blockIdx.z;
    int t = z >> 2, h = z & 3;
    size_t qoff = (size_t)t * (size_t)qkv_stride;
    const float* tmt = tm + (size_t)(t + (t >> 1)) * 262144;
    int toff = toff0 + t * 128;

    __shared__ unsigned short Vt[32][516];
    __shared__ unsigned short Ps[8][16][72];

    int tid = threadIdx.x, lane = tid & 63, wv = tid >> 6;
    int l15 = lane & 15, quad = lane >> 4;

    {
        const unsigned short* vp = v_ws + qoff + ((size_t)bp * 512 + tid) * 128 + h * 32;
        short8 a = *(const short8*)vp;
        short8 b = *(const short8*)(vp + 8);
        short8 c = *(const short8*)(vp + 16);
        short8 d = *(const short8*)(vp + 24);
        #pragma unroll
        for (int j = 0; j < 8; ++j) {
            Vt[j][tid]      = (unsigned short)a[j];
            Vt[8 + j][tid]  = (unsigned short)b[j];
            Vt[16 + j][tid] = (unsigned short)c[j];
            Vt[24 + j][tid] = (unsigned short)d[j];
        }
    }
    int n0 = nc2 * 256 + wv * 16;              // strip 0; strip 1 at n0+128
    short8 qf[2];
    qf[0] = *(const short8*)&q_ws[qoff +
        ((size_t)bp * 512 + n0 + l15) * 128 + h * 32 + quad * 8];
    qf[1] = *(const short8*)&q_ws[qoff +
        ((size_t)bp * 512 + n0 + 128 + l15) * 128 + h * 32 + quad * 8];
    __syncthreads();

    const unsigned short* Kb = k_ws + qoff + (size_t)bp * 512 * 128 + h * 32;
    floatx4 O0[2] = {{0.f,0.f,0.f,0.f},{0.f,0.f,0.f,0.f}};
    floatx4 O1[2] = {{0.f,0.f,0.f,0.f},{0.f,0.f,0.f,0.f}};
    float za[2][4] = {{0.f,0.f,0.f,0.f},{0.f,0.f,0.f,0.f}};
    const floatx4 zero4 = {0.f, 0.f, 0.f, 0.f};

    for (int c = 0; c < 8; ++c) {
        int mb = c * 64;
        short8 kf0 = *(const short8*)&Kb[(size_t)(mb +  0 + l15) * 128 + quad * 8];
        short8 kf1 = *(const short8*)&Kb[(size_t)(mb + 16 + l15) * 128 + quad * 8];
        short8 kf2 = *(const short8*)&Kb[(size_t)(mb + 32 + l15) * 128 + quad * 8];
        short8 kf3 = *(const short8*)&Kb[(size_t)(mb + 48 + l15) * 128 + quad * 8];

        #pragma unroll
        for (int s = 0; s < 2; ++s) {
            int ns = n0 + s * 128;
            floatx4 S[4];
            S[0] = __builtin_amdgcn_mfma_f32_16x16x32_bf16(qf[s], kf0, zero4, 0, 0, 0);
            S[1] = __builtin_amdgcn_mfma_f32_16x16x32_bf16(qf[s], kf1, zero4, 0, 0, 0);
            S[2] = __builtin_amdgcn_mfma_f32_16x16x32_bf16(qf[s], kf2, zero4, 0, 0, 0);
            S[3] = __builtin_amdgcn_mfma_f32_16x16x32_bf16(qf[s], kf3, zero4, 0, 0, 0);

            #pragma unroll
            for (int ti = 0; ti < 4; ++ti) {
                int m = mb + ti * 16 + l15;
                #pragma unroll
                for (int i = 0; i < 4; ++i) {
                    float tmv = tmt[(size_t)(ns + quad * 4 + i) * 512 + m];
                    float e = __builtin_amdgcn_exp2f(S[ti][i]);
                    za[s][i] += (tmv != 0.0f) ? e : 0.0f;
                    float w = e * tmv;                    // ==0 when masked
                    Ps[wv][quad * 4 + i][ti * 16 + l15] =
                        (unsigned short)((fbits(w) + 0x8000u) >> 16);  // half-up
                }
            }
            #pragma unroll
            for (int kc = 0; kc < 2; ++kc) {
                short8 pa  = *(const short8*)&Ps[wv][l15][kc * 32 + quad * 8];
                short8 vb0 = *(const short8*)&Vt[l15][mb + kc * 32 + quad * 8];
                short8 vb1 = *(const short8*)&Vt[16 + l15][mb + kc * 32 + quad * 8];
                O0[s] = __builtin_amdgcn_mfma_f32_16x16x32_bf16(pa, vb0, O0[s], 0, 0, 0);
                O1[s] = __builtin_amdgcn_mfma_f32_16x16x32_bf16(pa, vb1, O1[s], 0, 0, 0);
            }
        }
    }

    #pragma unroll
    for (int s = 0; s < 2; ++s) {
        #pragma unroll
        for (int d = 1; d < 16; d <<= 1) {
            #pragma unroll
            for (int i = 0; i < 4; ++i) za[s][i] += __shfl_xor(za[s][i], d, 64);
        }
        #pragma unroll
        for (int i = 0; i < 4; ++i) {
            float rz = 1.0f / za[s][i];
            size_t row = (size_t)bp * 512 + n0 + s * 128 + quad * 4 + i;
            att_ws[row * 384 + toff + h * 32 + l15]      = f2b(O0[s][i] * rz);
            att_ws[row * 384 + toff + h * 32 + 16 + l15] = f2b(O1[s][i] * rz);
        }
    }
}

// ---------------- K3a: out-projection from pre-converted Wo (proven) ----------
__global__ __launch_bounds__(256) void k_oproj_pre(
    const unsigned short* __restrict__ att_ws,   // [32][512][384] bf16
    const unsigned short* __restrict__ Wob,      // [128][384] bf16
    const float* __restrict__ X,
    const float* __restrict__ gamma,
    const float* __restrict__ beta,
    float* __restrict__ out)
{
    int bp = blockIdx.x;
    int mt = blockIdx.y;
    __shared__ unsigned short As[64 * 128];
    __shared__ unsigned short Ws[128 * 128];
    int tid = threadIdx.x, lane = tid & 63, wv = tid >> 6;
    int l15 = lane & 15, quad = lane >> 4;

    floatx4 acc[8];
    for (int ct = 0; ct < 8; ++ct) acc[ct] = (floatx4){0.f, 0.f, 0.f, 0.f};
    size_t rowbase = (size_t)bp * 512 + mt * 64;

    for (int kc = 0; kc < 3; ++kc) {
        __syncthreads();
        for (int i = 0; i < 4; ++i) {
            int flat = i * 256 + tid;
            int row = flat >> 4, colg = (flat & 15) * 8;
            *(short8*)&As[row * 128 + colg] =
                *(const short8*)&att_ws[(rowbase + row) * 384 + kc * 128 + colg];
        }
        for (int i = 0; i < 8; ++i) {
            int flat = i * 256 + tid;
            int row = flat >> 4, colg = (flat & 15) * 8;
            *(short8*)&Ws[row * 128 + colg] =
                *(const short8*)&Wob[(size_t)row * 384 + kc * 128 + colg];
        }
        __syncthreads();
        for (int ct = 0; ct < 8; ++ct) {
            for (int kk = 0; kk < 4; ++kk) {
                short8 a = *(const short8*)&As[(wv * 16 + l15) * 128 + kk * 32 + quad * 8];
                short8 b = *(const short8*)&Ws[(ct * 16 + l15) * 128 + kk * 32 + quad * 8];
                acc[ct] = __builtin_amdgcn_mfma_f32_16x16x32_bf16(a, b, acc[ct], 0, 0, 0);
            }
        }
    }

    for (int i = 0; i < 4; ++i) {
        int lrow = wv * 16 + quad * 4 + i;
        size_t grow = rowbase + lrow;
        float vals[8];
        float s = 0.f, sq = 0.f;
        for (int ct = 0; ct < 8; ++ct) {
            int col = ct * 16 + l15;
            float v = acc[ct][i] + X[grow * 128 + col];
            vals[ct] = v;
            s += v; sq += v * v;
        }
        for (int d = 1; d < 16; d <<= 1) {
            s  += __shfl_xor(s, d, 64);
            sq += __shfl_xor(sq, d, 64);
        }
        float mu = s * (1.0f / 128.0f);
        float var = sq * (1.0f / 128.0f) - mu * mu;
        float rs = rsqrtf(var + 1e-5f);
        for (int ct = 0; ct < 8; ++ct) {
            int col = ct * 16 + l15;
            out[grow * 128 + col] = (vals[ct] - mu) * rs * gamma[col] + beta[col];
        }
    }
}

// ---------------- K3b: out-projection, inline-cvt fallback --------------------
__global__ __launch_bounds__(256) void k_oproj_cvt(
    const unsigned short* __restrict__ att_ws,
    const float* __restrict__ Wo,
    const float* __restrict__ X,
    const float* __restrict__ gamma,
    const float* __restrict__ beta,
    float* __restrict__ out)
{
    int bp = blockIdx.x;
    int mt = blockIdx.y;
    __shared__ unsigned short As[64 * 128];
    __shared__ unsigned short Ws[128 * 128];
    int tid = threadIdx.x, lane = tid & 63, wv = tid >> 6;
    int l15 = lane & 15, quad = lane >> 4;

    floatx4 acc[8];
    for (int ct = 0; ct < 8; ++ct) acc[ct] = (floatx4){0.f, 0.f, 0.f, 0.f};
    size_t rowbase = (size_t)bp * 512 + mt * 64;

    for (int kc = 0; kc < 3; ++kc) {
        __syncthreads();
        for (int i = 0; i < 4; ++i) {
            int flat = i * 256 + tid;
            int row = flat >> 4, colg = (flat & 15) * 8;
            *(short8*)&As[row * 128 + colg] =
                *(const short8*)&att_ws[(rowbase + row) * 384 + kc * 128 + colg];
        }
        for (int i = 0; i < 8; ++i) {
            int flat = i * 256 + tid;
            int row = flat >> 4, colg = (flat & 15) * 8;
            *(short8*)&Ws[row * 128 + colg] = cvt8(&Wo[(size_t)row * 384 + kc * 128 + colg]);
        }
        __syncthreads();
        for (int ct = 0; ct < 8; ++ct) {
            for (int kk = 0; kk < 4; ++kk) {
                short8 a = *(const short8*)&As[(wv * 16 + l15) * 128 + kk * 32 + quad * 8];
                short8 b = *(const short8*)&Ws[(ct * 16 + l15) * 128 + kk * 32 + quad * 8];
                acc[ct] = __builtin_amdgcn_mfma_f32_16x16x32_bf16(a, b, acc[ct], 0, 0, 0);
            }
        }
    }

    for (int i = 0; i < 4; ++i) {
        int lrow = wv * 16 + quad * 4 + i;
        size_t grow = rowbase + lrow;
        float vals[8];
        float s = 0.f, sq = 0.f;
        for (int ct = 0; ct < 8; ++ct) {
            int col = ct * 16 + l15;
            float v = acc[ct][i] + X[grow * 128 + col];
            vals[ct] = v;
            s += v; sq += v * v;
        }
        for (int d = 1; d < 16; d <<= 1) {
            s  += __shfl_xor(s, d, 64);
            sq += __shfl_xor(sq, d, 64);
        }
        float mu = s * (1.0f / 128.0f);
        float var = sq * (1.0f / 128.0f) - mu * mu;
        float rs = rsqrtf(var + 1e-5f);
        for (int ct = 0; ct < 8; ++ct) {
            int col = ct * 16 + l15;
            out[grow * 128 + col] = (vals[ct] - mu) * rs * gamma[col] + beta[col];
        }
    }
}

// ---------------- launcher ----------------
extern "C" void kernel_launch(void* const* d_in, const int* in_sizes, int n_in,
                              void* d_out, int out_size, void* d_ws, size_t ws_size,
                              hipStream_t stream) {
    const float* X     = (const float*)d_in[0];
    const float* TM    = (const float*)d_in[2];
    const float* Wq    = (const float*)d_in[3];
    const float* Wk    = (const float*)d_in[4];
    const float* Wv    = (const float*)d_in[5];
    const float* Wo    = (const float*)d_in[6];
    const float* gamma = (const float*)d_in[7];
    const float* beta  = (const float*)d_in[8];
    float* out = (float*)d_out;

    char* ws = (char*)d_ws;
    const size_t QKV1 = 2097152;             // elems per t per tensor
    const size_t QKV1B = QKV1 * 2;           // 4 MB

    if (ws_size >= WS_XL) {
        unsigned short* q3  = (unsigned short*)(ws);
        unsigned short* k3  = (unsigned short*)(ws + 3 * QKV1B);
        unsigned short* v3  = (unsigned short*)(ws + 6 * QKV1B);
        unsigned short* att = (unsigned short*)(ws + 9 * QKV1B);
        unsigned short* Xb  = (unsigned short*)(ws + 50331648ull);
        unsigned short* Wb  = (unsigned short*)(ws + 54525952ull);
        unsigned short* Wob = (unsigned short*)(ws + 54820864ull);
        k_prep<<<dim3(1120), 256, 0, stream>>>(X, Wq, Wk, Wv, Wo, Xb, Wb, Wob);
        k_qkv_pre<<<dim3(32, 4, 3), 256, 0, stream>>>(Xb, Wb, q3, k3, v3);
        k_attn2<<<dim3(2, 32, 12), 512, 0, stream>>>(q3, k3, v3, TM, att, (int)QKV1, 0);
        k_oproj_pre<<<dim3(32, 8), 256, 0, stream>>>(att, Wob, X, gamma, beta, out);
    } else if (ws_size >= WS_BIG) {
        unsigned short* q3  = (unsigned short*)(ws);
        unsigned short* k3  = (unsigned short*)(ws + 3 * QKV1B);
        unsigned short* v3  = (unsigned short*)(ws + 6 * QKV1B);
        unsigned short* att = (unsigned short*)(ws + 9 * QKV1B);
        k_qkv_cvt<<<dim3(32, 4, 3), 256, 0, stream>>>(
            X, Wq, Wk, Wv, q3, k3, v3, 16384, (int)QKV1);
        k_attn2<<<dim3(2, 32, 12), 512, 0, stream>>>(q3, k3, v3, TM, att, (int)QKV1, 0);
        k_oproj_cvt<<<dim3(32, 8), 256, 0, stream>>>(att, Wo, X, gamma, beta, out);
    } else {
        unsigned short* q_ws   = (unsigned short*)(ws);
        unsigned short* k_ws   = (unsigned short*)(ws + QKV1B);
        unsigned short* v_ws   = (unsigned short*)(ws + 2 * QKV1B);
        unsigned short* att_ws = (unsigned short*)(ws + 3 * QKV1B);
        const int tsel[3] = {0, 1, 3};
        for (int t = 0; t < 3; ++t) {
            k_qkv_cvt<<<dim3(32, 4, 1), 256, 0, stream>>>(
                X, Wq + (size_t)t * 16384, Wk + (size_t)t * 16384, Wv + (size_t)t * 16384,
                q_ws, k_ws, v_ws, 0, 0);
            k_attn2<<<dim3(2, 32, 4), 512, 0, stream>>>(
                q_ws, k_ws, v_ws, TM + (size_t)tsel[t] * 262144, att_ws, 0, t * 128);
        }
        k_oproj_cvt<<<dim3(32, 8), 256, 0, stream>>>(att_ws, Wo, X, gamma, beta, out);
    }
}